// Round 12
// baseline (55.913 us; speedup 1.0000x reference)
//
#include <hip/hip_runtime.h>
#include <cmath>
#include <cstring>

// SPD log(A), 8192 64x64 SPD matrices.
// Degree-6 Chebyshev poly on [0.5,5.8] in Y=(A-mI)/r, 3 matmuls:
//   P2=Y*Y, P3=Y*P2 (fused R1 = a6 P3 + a5 P2 + a4 Y + a3 I),
//   out = P3*R1 + (a2 P2 + a1 Y + a0 I).
// Round 12: round-8 structure + NONTEMPORAL output stores (f32x4 ext-vector;
// HIP float4 is rejected by the builtin). Output is never re-read; nt stores
// keep the 131MB output stream from evicting the 134MB input from L3 across
// graph replays -> input stays L3-resident (FETCH->0), read path at L3
// speed, write path streams to HBM.
// Pure-f16 operands; f32 MFMA accumulate; yv/pv register-hoisted.
// 4 LDS planes = 32KB -> 5 blocks/CU. All matrices symmetric (polynomials
// in Y) => A/B-fragments read as row slices; stores transposed. XOR-swizzle.

typedef _Float16 half8 __attribute__((ext_vector_type(8)));
typedef _Float16 half4 __attribute__((ext_vector_type(4)));
typedef float f32x4 __attribute__((ext_vector_type(4)));

struct Coefs { float a[8]; float m, invr; };

#define PL_Y  0
#define PL_P2 8192
#define PL_P3 16384
#define PL_R1 24576
#define LDS_BYTES 32768

__device__ __forceinline__ int swz(int row, int bytecol) {
  return row * 128 + (bytecol ^ ((row & 7) << 4));
}

__device__ __forceinline__ half8 read_frag(const char* lds, int plane,
                                           int band, int s, int lane) {
  int row = band * 16 + (lane & 15);
  int bc = s * 64 + ((lane >> 4) << 4);
  return *(const half8*)(lds + plane + swz(row, bc));
}

#define MFMA16(a, b, c) __builtin_amdgcn_mfma_f32_16x16x32_f16((a), (b), (c), 0, 0, 0)

__global__ __launch_bounds__(256, 5) void spdlog64(const float* __restrict__ A,
                                                   float* __restrict__ O,
                                                   Coefs cf) {
  __shared__ __align__(16) char lds[LDS_BYTES];
  const int t = threadIdx.x;
  const int lane = t & 63;
  const int w = t >> 6;               // band: 16 rows per wave
  const float* Ab = A + (size_t)blockIdx.x * 4096;
  float* Ob = O + (size_t)blockIdx.x * 4096;

  // ---- load A, form Y = (A - m I)*invr, f16 RTNE ----
  #pragma unroll
  for (int i = 0; i < 4; ++i) {
    int q = t + 256 * i;              // float4 index 0..1023
    float4 v = ((const float4*)Ab)[q];
    int row = q >> 4, col = (q & 15) << 2;
    half4 h;
    h[0] = (_Float16)((v.x - (col + 0 == row ? cf.m : 0.f)) * cf.invr);
    h[1] = (_Float16)((v.y - (col + 1 == row ? cf.m : 0.f)) * cf.invr);
    h[2] = (_Float16)((v.z - (col + 2 == row ? cf.m : 0.f)) * cf.invr);
    h[3] = (_Float16)((v.w - (col + 3 == row ? cf.m : 0.f)) * cf.invr);
    *(half4*)(lds + PL_Y + swz(row, col * 2)) = h;
  }
  __syncthreads();                    // barrier 1

  // tile geometry: tile f covers rows r0..r0+3, col c = f*16 + (lane&15);
  // transposed store/epi offset = swz(c, r0*2).
  const int r0 = w * 16 + ((lane >> 4) << 2);
  const int cB = lane & 15;

  f32x4 acc[4];
  half4 yv[4], pv[4];

  // ---- stage 1: P2 = Y*Y; pv from acc regs; yv hoisted ----
  #pragma unroll
  for (int f = 0; f < 4; ++f) acc[f] = (f32x4)0.f;
  #pragma unroll
  for (int s = 0; s < 2; ++s) {
    half8 Av = read_frag(lds, PL_Y, w, s, lane);
    #pragma unroll
    for (int f = 0; f < 4; ++f) {
      half8 Bv = read_frag(lds, PL_Y, f, s, lane);
      acc[f] = MFMA16(Av, Bv, acc[f]);
    }
  }
  #pragma unroll
  for (int f = 0; f < 4; ++f) {
    int c = f * 16 + cB;
    int off = swz(c, r0 * 2);
    half4 p = {(_Float16)acc[f][0], (_Float16)acc[f][1],
               (_Float16)acc[f][2], (_Float16)acc[f][3]};
    *(half4*)(lds + PL_P2 + off) = p;
    pv[f] = p;
    yv[f] = *(const half4*)(lds + PL_Y + off);  // read-only this pass: no race
  }
  __syncthreads();                    // barrier 2

  // ---- stage 2: P3 = Y*P2, fused R1 = a6*P3 + a5*P2 + a4*Y + a3*I ----
  #pragma unroll
  for (int f = 0; f < 4; ++f) acc[f] = (f32x4)0.f;
  #pragma unroll
  for (int s = 0; s < 2; ++s) {
    half8 Av = read_frag(lds, PL_Y, w, s, lane);
    #pragma unroll
    for (int f = 0; f < 4; ++f) {
      half8 Bv = read_frag(lds, PL_P2, f, s, lane);
      acc[f] = MFMA16(Av, Bv, acc[f]);
    }
  }
  #pragma unroll
  for (int f = 0; f < 4; ++f) {
    int c = f * 16 + cB;
    int off = swz(c, r0 * 2);
    half4 p3, r1;
    #pragma unroll
    for (int j = 0; j < 4; ++j) {
      p3[j] = (_Float16)acc[f][j];
      float rv = cf.a[6] * acc[f][j] + cf.a[4] * (float)yv[f][j] +
                 cf.a[5] * (float)pv[f][j];
      if (r0 + j == c) rv += cf.a[3];
      r1[j] = (_Float16)rv;
    }
    *(half4*)(lds + PL_P3 + off) = p3;
    *(half4*)(lds + PL_R1 + off) = r1;
  }
  __syncthreads();                    // barrier 3

  // ---- stage 3: out = P3*R1 + (a0 I + a1 Y + a2 P2) -> global (nt) ----
  #pragma unroll
  for (int f = 0; f < 4; ++f) acc[f] = (f32x4)0.f;
  #pragma unroll
  for (int s = 0; s < 2; ++s) {
    half8 Av = read_frag(lds, PL_P3, w, s, lane);
    #pragma unroll
    for (int f = 0; f < 4; ++f) {
      half8 Bv = read_frag(lds, PL_R1, f, s, lane);
      acc[f] = MFMA16(Av, Bv, acc[f]);
    }
  }
  #pragma unroll
  for (int f = 0; f < 4; ++f) {
    int c = f * 16 + cB;
    f32x4 o;
    #pragma unroll
    for (int j = 0; j < 4; ++j) {
      float v = acc[f][j] + cf.a[1] * (float)yv[f][j] +
                cf.a[2] * (float)pv[f][j];
      if (r0 + j == c) v += cf.a[0];
      o[j] = v;
    }
    // nontemporal: output never re-read; don't pollute L2/L3
    __builtin_nontemporal_store(o, (f32x4*)(Ob + (size_t)c * 64 + r0));
  }
}

extern "C" void kernel_launch(void* const* d_in, const int* in_sizes, int n_in,
                              void* d_out, int out_size, void* d_ws, size_t ws_size,
                              hipStream_t stream) {
  (void)n_in; (void)out_size; (void)d_ws; (void)ws_size;
  const float* A = (const float*)d_in[0];
  float* O = (float*)d_out;
  const int nb = in_sizes[0] / 4096;

  // Chebyshev series of log(x) on [lo,hi], degree 6, closed form:
  // x = m(1 + rho t); log = (log m - log(1+z^2)) + 2*sum (-1)^{k+1} z^k/k T_k(t)
  const double lo = 0.5, hi = 5.8;
  const double m = 0.5 * (lo + hi), r = 0.5 * (hi - lo), rho = r / m;
  const double sq = std::sqrt(1.0 - rho * rho);
  const double z = (1.0 - sq) / rho;
  const int D = 6;
  double c[8];
  c[0] = std::log(m) - std::log1p(z * z);
  double zk = z;
  for (int k = 1; k <= D; ++k) {
    c[k] = 2.0 * ((k & 1) ? 1.0 : -1.0) * zk / (double)k;
    zk *= z;
  }
  // Chebyshev -> monomial in t
  double Tp[8] = {0}, Tc[8] = {0}, Tn[8];
  double am[8] = {0};
  Tp[0] = 1.0;
  am[0] += c[0];
  Tc[1] = 1.0;
  am[1] += c[1];
  for (int k = 2; k <= D; ++k) {
    for (int j = 0; j < 8; ++j) Tn[j] = (j ? 2.0 * Tc[j - 1] : 0.0) - Tp[j];
    for (int j = 0; j < 8; ++j) am[j] += c[k] * Tn[j];
    std::memcpy(Tp, Tc, sizeof Tp);
    std::memcpy(Tc, Tn, sizeof Tc);
  }
  Coefs cf;
  for (int j = 0; j < 8; ++j) cf.a[j] = (float)am[j];
  cf.m = (float)m;
  cf.invr = (float)(1.0 / r);

  spdlog64<<<nb, 256, 0, stream>>>(A, O, cf);
}

// Round 13
// 45.915 us; speedup vs baseline: 1.2177x; 1.2177x over previous
//
#include <hip/hip_runtime.h>
#include <cmath>
#include <cstring>

// SPD log(A), 8192 64x64 SPD matrices.
// Degree-6 Chebyshev poly on [0.5,5.8] in Y=(A-mI)/r, 3 matmuls:
//   P2=Y*Y, P3=Y*P2 (fused R1 = a6 P3 + a5 P2 + a4 Y + a3 I),
//   out = P3*R1 + (a2 P2 + a1 Y + a0 I).
// Round 13: exact revert to the round-8 kernel (measured best, 45.9us).
// Verdict from R7-R12: memory-system-bound at ~5.8 TB/s composite (92% of
// the 6.29 TB/s D2D ceiling); nt stores amplify writes (R12), prefetch
// pipelining spills (R9), more occupancy doesn't help (R10).
// Pure-f16 operands; f32 MFMA accumulate; yv/pv register-hoisted.
// 4 LDS planes = 32KB -> 5 blocks/CU. All matrices symmetric (polynomials
// in Y) => A/B-fragments read as row slices; stores transposed. XOR-swizzle.

typedef _Float16 half8 __attribute__((ext_vector_type(8)));
typedef _Float16 half4 __attribute__((ext_vector_type(4)));
typedef float f32x4 __attribute__((ext_vector_type(4)));

struct Coefs { float a[8]; float m, invr; };

#define PL_Y  0
#define PL_P2 8192
#define PL_P3 16384
#define PL_R1 24576
#define LDS_BYTES 32768

__device__ __forceinline__ int swz(int row, int bytecol) {
  return row * 128 + (bytecol ^ ((row & 7) << 4));
}

__device__ __forceinline__ half8 read_frag(const char* lds, int plane,
                                           int band, int s, int lane) {
  int row = band * 16 + (lane & 15);
  int bc = s * 64 + ((lane >> 4) << 4);
  return *(const half8*)(lds + plane + swz(row, bc));
}

#define MFMA16(a, b, c) __builtin_amdgcn_mfma_f32_16x16x32_f16((a), (b), (c), 0, 0, 0)

__global__ __launch_bounds__(256, 5) void spdlog64(const float* __restrict__ A,
                                                   float* __restrict__ O,
                                                   Coefs cf) {
  __shared__ __align__(16) char lds[LDS_BYTES];
  const int t = threadIdx.x;
  const int lane = t & 63;
  const int w = t >> 6;               // band: 16 rows per wave
  const float* Ab = A + (size_t)blockIdx.x * 4096;
  float* Ob = O + (size_t)blockIdx.x * 4096;

  // ---- load A, form Y = (A - m I)*invr, f16 RTNE ----
  #pragma unroll
  for (int i = 0; i < 4; ++i) {
    int q = t + 256 * i;              // float4 index 0..1023
    float4 v = ((const float4*)Ab)[q];
    int row = q >> 4, col = (q & 15) << 2;
    half4 h;
    h[0] = (_Float16)((v.x - (col + 0 == row ? cf.m : 0.f)) * cf.invr);
    h[1] = (_Float16)((v.y - (col + 1 == row ? cf.m : 0.f)) * cf.invr);
    h[2] = (_Float16)((v.z - (col + 2 == row ? cf.m : 0.f)) * cf.invr);
    h[3] = (_Float16)((v.w - (col + 3 == row ? cf.m : 0.f)) * cf.invr);
    *(half4*)(lds + PL_Y + swz(row, col * 2)) = h;
  }
  __syncthreads();                    // barrier 1

  // tile geometry: tile f covers rows r0..r0+3, col c = f*16 + (lane&15);
  // transposed store/epi offset = swz(c, r0*2).
  const int r0 = w * 16 + ((lane >> 4) << 2);
  const int cB = lane & 15;

  f32x4 acc[4];
  half4 yv[4], pv[4];

  // ---- stage 1: P2 = Y*Y; pv from acc regs; yv hoisted ----
  #pragma unroll
  for (int f = 0; f < 4; ++f) acc[f] = (f32x4)0.f;
  #pragma unroll
  for (int s = 0; s < 2; ++s) {
    half8 Av = read_frag(lds, PL_Y, w, s, lane);
    #pragma unroll
    for (int f = 0; f < 4; ++f) {
      half8 Bv = read_frag(lds, PL_Y, f, s, lane);
      acc[f] = MFMA16(Av, Bv, acc[f]);
    }
  }
  #pragma unroll
  for (int f = 0; f < 4; ++f) {
    int c = f * 16 + cB;
    int off = swz(c, r0 * 2);
    half4 p = {(_Float16)acc[f][0], (_Float16)acc[f][1],
               (_Float16)acc[f][2], (_Float16)acc[f][3]};
    *(half4*)(lds + PL_P2 + off) = p;
    pv[f] = p;
    yv[f] = *(const half4*)(lds + PL_Y + off);  // read-only this pass: no race
  }
  __syncthreads();                    // barrier 2

  // ---- stage 2: P3 = Y*P2, fused R1 = a6*P3 + a5*P2 + a4*Y + a3*I ----
  #pragma unroll
  for (int f = 0; f < 4; ++f) acc[f] = (f32x4)0.f;
  #pragma unroll
  for (int s = 0; s < 2; ++s) {
    half8 Av = read_frag(lds, PL_Y, w, s, lane);
    #pragma unroll
    for (int f = 0; f < 4; ++f) {
      half8 Bv = read_frag(lds, PL_P2, f, s, lane);
      acc[f] = MFMA16(Av, Bv, acc[f]);
    }
  }
  #pragma unroll
  for (int f = 0; f < 4; ++f) {
    int c = f * 16 + cB;
    int off = swz(c, r0 * 2);
    half4 p3, r1;
    #pragma unroll
    for (int j = 0; j < 4; ++j) {
      p3[j] = (_Float16)acc[f][j];
      float rv = cf.a[6] * acc[f][j] + cf.a[4] * (float)yv[f][j] +
                 cf.a[5] * (float)pv[f][j];
      if (r0 + j == c) rv += cf.a[3];
      r1[j] = (_Float16)rv;
    }
    *(half4*)(lds + PL_P3 + off) = p3;
    *(half4*)(lds + PL_R1 + off) = r1;
  }
  __syncthreads();                    // barrier 3

  // ---- stage 3: out = P3*R1 + (a0 I + a1 Y + a2 P2) -> global ----
  #pragma unroll
  for (int f = 0; f < 4; ++f) acc[f] = (f32x4)0.f;
  #pragma unroll
  for (int s = 0; s < 2; ++s) {
    half8 Av = read_frag(lds, PL_P3, w, s, lane);
    #pragma unroll
    for (int f = 0; f < 4; ++f) {
      half8 Bv = read_frag(lds, PL_R1, f, s, lane);
      acc[f] = MFMA16(Av, Bv, acc[f]);
    }
  }
  #pragma unroll
  for (int f = 0; f < 4; ++f) {
    int c = f * 16 + cB;
    float4 o;
    float* op = &o.x;
    #pragma unroll
    for (int j = 0; j < 4; ++j) {
      float v = acc[f][j] + cf.a[1] * (float)yv[f][j] +
                cf.a[2] * (float)pv[f][j];
      if (r0 + j == c) v += cf.a[0];
      op[j] = v;
    }
    *(float4*)(Ob + (size_t)c * 64 + r0) = o;   // transposed (symmetric)
  }
}

extern "C" void kernel_launch(void* const* d_in, const int* in_sizes, int n_in,
                              void* d_out, int out_size, void* d_ws, size_t ws_size,
                              hipStream_t stream) {
  (void)n_in; (void)out_size; (void)d_ws; (void)ws_size;
  const float* A = (const float*)d_in[0];
  float* O = (float*)d_out;
  const int nb = in_sizes[0] / 4096;

  // Chebyshev series of log(x) on [lo,hi], degree 6, closed form:
  // x = m(1 + rho t); log = (log m - log(1+z^2)) + 2*sum (-1)^{k+1} z^k/k T_k(t)
  const double lo = 0.5, hi = 5.8;
  const double m = 0.5 * (lo + hi), r = 0.5 * (hi - lo), rho = r / m;
  const double sq = std::sqrt(1.0 - rho * rho);
  const double z = (1.0 - sq) / rho;
  const int D = 6;
  double c[8];
  c[0] = std::log(m) - std::log1p(z * z);
  double zk = z;
  for (int k = 1; k <= D; ++k) {
    c[k] = 2.0 * ((k & 1) ? 1.0 : -1.0) * zk / (double)k;
    zk *= z;
  }
  // Chebyshev -> monomial in t
  double Tp[8] = {0}, Tc[8] = {0}, Tn[8];
  double am[8] = {0};
  Tp[0] = 1.0;
  am[0] += c[0];
  Tc[1] = 1.0;
  am[1] += c[1];
  for (int k = 2; k <= D; ++k) {
    for (int j = 0; j < 8; ++j) Tn[j] = (j ? 2.0 * Tc[j - 1] : 0.0) - Tp[j];
    for (int j = 0; j < 8; ++j) am[j] += c[k] * Tn[j];
    std::memcpy(Tp, Tc, sizeof Tp);
    std::memcpy(Tc, Tn, sizeof Tc);
  }
  Coefs cf;
  for (int j = 0; j < 8; ++j) cf.a[j] = (float)am[j];
  cf.m = (float)m;
  cf.invr = (float)(1.0 / r);

  spdlog64<<<nb, 256, 0, stream>>>(A, O, cf);
}